// Round 7
// baseline (328.302 us; speedup 1.0000x reference)
//
#include <hip/hip_runtime.h>
#include <hip/hip_bf16.h>
#include <stdint.h>

// ExpanderLinear: y[t,o] = sum_i x[t,i] * (w[o,i]*mask[o,i]) + bias[o]
// M=8192, K=4096, N=4096. f32 in/out, bf16 MFMA compute.
// GEMM: 256x256 tile, 8 waves, ring-4 half-K LDS units (128 KiB), T1+T2+T5.
// R7 change: ONE sync point per K-tile ({vmcnt(0); s_barrier} at tile top),
// no intra-tile barriers -- stages issue first, then 24 ds_reads + 64 MFMA
// free-run so the compiler + inter-wave drift overlap LDS pipe with MFMA pipe.

typedef __attribute__((ext_vector_type(4))) float          f32x4;
typedef __attribute__((ext_vector_type(4))) int            i32x4;
typedef __attribute__((ext_vector_type(4))) unsigned short u16x4;
typedef __attribute__((ext_vector_type(8))) __bf16         bf16x8;

static constexpr int M = 8192;
static constexpr int N = 4096;
static constexpr int K = 4096;

#define BM 256
#define BN 256
#define NT (K / 64)

#define GLOBAL_AS(p) ((const __attribute__((address_space(1))) void*)(p))
#define LDS_AS(p)    ((__attribute__((address_space(3))) void*)(p))

__device__ __forceinline__ unsigned short f2bf(float f) {
    unsigned int u = __float_as_uint(f);
    u = (u + 0x7fffu + ((u >> 16) & 1u)) >> 16;
    return (unsigned short)u;
}

// ---- prep 1: x f32 -> bf16 ----
__global__ void cvt_x_kernel(const float* __restrict__ x,
                             unsigned short* __restrict__ out) {
    int i = blockIdx.x * blockDim.x + threadIdx.x;
    f32x4 v = ((const f32x4*)x)[i];
    u16x4 r;
    r.x = f2bf(v.x); r.y = f2bf(v.y); r.z = f2bf(v.z); r.w = f2bf(v.w);
    ((u16x4*)out)[i] = r;
}

// ---- prep 2: (w * mask) f32 -> bf16, fused ----
__global__ void cvt_wm_kernel(const float* __restrict__ w,
                              const int* __restrict__ mask,
                              unsigned short* __restrict__ out) {
    int i = blockIdx.x * blockDim.x + threadIdx.x;
    f32x4 v = ((const f32x4*)w)[i];
    i32x4 m = ((const i32x4*)mask)[i];
    u16x4 r;
    r.x = m.x ? f2bf(v.x) : (unsigned short)0;
    r.y = m.y ? f2bf(v.y) : (unsigned short)0;
    r.z = m.z ? f2bf(v.z) : (unsigned short)0;
    r.w = m.w ? f2bf(v.w) : (unsigned short)0;
    ((u16x4*)out)[i] = r;
}

// ---- main GEMM ----
// LDS: A-ring = 4 units of [256 rows][32 bf16] (16KB each), B-ring same.
// Unit for (tile t, k-half h) lives in slot (2t+h)&3.
// Per K-tile: {vmcnt(0); barrier; stage t+1 (8 gloads); 24 ds_read_b128 +
// 64 MFMA free-run}. Stage slots {2t+2,2t+3}&3 were last read at t-1
// (separated by this tile's barrier); this tile's units were staged at t-1
// (retired by the vmcnt(0), aged ~1 full K-tile -> no stall).
// Swizzle (within 128B row-pair): phys3 = (((row&1)<<2)|fq) ^ ((row>>1)&7).
// LDS writes stay linear (global_load_lds); global SOURCE pre-swizzled.
__global__ void __launch_bounds__(512, 2)
gemm8_bf16(const unsigned short* __restrict__ A,   // [M][K] bf16 bits
           const unsigned short* __restrict__ B,   // [N][K] bf16 bits
           const float* __restrict__ bias,         // [N]
           float* __restrict__ C) {                // [M][N] f32
    extern __shared__ unsigned short lds[];
    unsigned short* __restrict__ Au = lds;            // 4 * 8192 elems
    unsigned short* __restrict__ Bu = lds + 32768;    // 4 * 8192 elems

    const int tid  = threadIdx.x;
    const int lane = tid & 63;
    const int wave = tid >> 6;

    // T1: XCD-aware bijective swizzle (nwg = 512, % 8 == 0)
    const int bid = blockIdx.x;
    const int swz = (bid & 7) * 64 + (bid >> 3);
    const int brow = (swz >> 4) * BM;          // ntn = 16
    const int bcol = (swz & 15) * BN;

    const int wrow = (wave >> 2) * 128;        // wave output rows
    const int wcol = (wave & 3) * 64;          // wave output cols
    const int fr = lane & 15;                  // fragment row/col
    const int fq = lane >> 4;                  // k-subgroup

    // read-side swizzle bases (byte offsets within a unit)
    const int s3r   = (((fr & 1) << 2) | fq) ^ (fr >> 1);
    const int abase = wrow * 64 + (fr >> 1) * 128 + s3r * 16;   // + m*1024
    const int bbase = wcol * 64 + (fr >> 1) * 128 + s3r * 16;   // + n*1024

    // write-side: lane's linear LDS slot -> logical (row, col) in global
    const int l8 = lane & 7, lh = lane >> 3;
    const int s3w    = l8 ^ lh;
    const int wrow_l = 2 * lh + (s3w >> 2);    // row within 16-row call block
    const int wcol_l = (s3w & 3) * 8;          // bf16 col within 32-col unit

    const unsigned short* __restrict__ Ag = A + (size_t)brow * K;
    const unsigned short* __restrict__ Bg = B + (size_t)bcol * K;

    f32x4 acc[8][4];
#pragma unroll
    for (int m = 0; m < 8; ++m)
#pragma unroll
        for (int n = 0; n < 4; ++n) acc[m][n] = (f32x4)(0.0f);

    bf16x8 af[4], bfv[4];

#define STG1(dst, src) __builtin_amdgcn_global_load_lds(GLOBAL_AS(src), LDS_AS(dst), 16, 0, 0)
#define STGA(slot, kcol) do {                                                   \
    STG1(Au + (slot) * 8192 + wave * 512,                                       \
         Ag + (size_t)(wave * 16 + wrow_l) * K + (kcol) + wcol_l);              \
    STG1(Au + (slot) * 8192 + (wave + 8) * 512,                                 \
         Ag + (size_t)((wave + 8) * 16 + wrow_l) * K + (kcol) + wcol_l);        \
  } while (0)
#define STGB(slot, kcol) do {                                                   \
    STG1(Bu + (slot) * 8192 + wave * 512,                                       \
         Bg + (size_t)(wave * 16 + wrow_l) * K + (kcol) + wcol_l);              \
    STG1(Bu + (slot) * 8192 + (wave + 8) * 512,                                 \
         Bg + (size_t)((wave + 8) * 16 + wrow_l) * K + (kcol) + wcol_l);        \
  } while (0)
#define LDA4(unit, m0) do {                                                     \
    const char* ub_ = (const char*)(Au + (unit) * 8192);                        \
    _Pragma("unroll")                                                           \
    for (int i = 0; i < 4; ++i)                                                 \
        af[i] = *(const bf16x8*)(ub_ + abase + ((m0) + i) * 1024);              \
  } while (0)
#define LDB4(unit) do {                                                         \
    const char* vb_ = (const char*)(Bu + (unit) * 8192);                        \
    _Pragma("unroll")                                                           \
    for (int n = 0; n < 4; ++n)                                                 \
        bfv[n] = *(const bf16x8*)(vb_ + bbase + n * 1024);                      \
  } while (0)
#define MM4(r0) do {                                                            \
    __builtin_amdgcn_s_setprio(1);                                              \
    _Pragma("unroll")                                                           \
    for (int i = 0; i < 4; ++i)                                                 \
      _Pragma("unroll")                                                         \
      for (int n = 0; n < 4; ++n)                                               \
        acc[(r0) + i][n] = __builtin_amdgcn_mfma_f32_16x16x32_bf16(             \
            af[i], bfv[n], acc[(r0) + i][n], 0, 0, 0);                          \
    __builtin_amdgcn_s_setprio(0);                                              \
  } while (0)
#define BAR   __builtin_amdgcn_s_barrier()
#define FENCE asm volatile("" ::: "memory")
#define WVM0  asm volatile("s_waitcnt vmcnt(0)" ::: "memory")

    // prologue: stage tile 0 (kh0->slot0, kh1->slot1)
    STGA(0, 0); STGB(0, 0);
    STGA(1, 32); STGB(1, 32);

    for (int t = 0; t < NT; ++t) {
        const int u0 = (2 * t) & 3;
        const int u1 = (2 * t + 1) & 3;
        const int s0 = (2 * t + 2) & 3;
        const int s1 = (2 * t + 3) & 3;
        const int kn = (t + 1 < NT) ? (t + 1) * 64 : 0;   // wrap: benign

        // single sync point: previous stages retired (aged ~1 K-tile -> no
        // stall) + all waves done reading the slots we're about to overwrite.
        WVM0; BAR; FENCE;

        if (t + 1 < NT) {                 // stage tile t+1 first (hides under
            STGA(s0, kn); STGB(s0, kn);   //  this whole tile's compute)
            STGA(s1, kn + 32); STGB(s1, kn + 32);
        }

        // free-run: 24 ds_read_b128 + 64 MFMA, compiler-scheduled fine-grained
        LDA4(u0, 0); LDB4(u0); MM4(0);
        LDA4(u0, 4);           MM4(4);
        LDA4(u1, 0); LDB4(u1); MM4(0);
        LDA4(u1, 4);           MM4(4);
    }
    WVM0;   // defensive drain before epilogue

    // epilogue: C/D layout col=lane&15, row=(lane>>4)*4+reg [m89/m91]
    float bv[4];
#pragma unroll
    for (int n = 0; n < 4; ++n) bv[n] = bias[bcol + wcol + n * 16 + fr];
#pragma unroll
    for (int m = 0; m < 8; ++m) {
#pragma unroll
        for (int j = 0; j < 4; ++j) {
            const int row = brow + wrow + m * 16 + fq * 4 + j;
            float* crow = C + (size_t)row * N + bcol + wcol + fr;
#pragma unroll
            for (int n = 0; n < 4; ++n) crow[n * 16] = acc[m][n][j] + bv[n];
        }
    }
#undef STG1
#undef STGA
#undef STGB
#undef LDA4
#undef LDB4
#undef MM4
#undef BAR
#undef FENCE
#undef WVM0
}

// ---- fallback (only if ws too small): f32 vector GEMM ----
__global__ void fallback_gemm(const float* __restrict__ x,
                              const float* __restrict__ w,
                              const int* __restrict__ mask,
                              const float* __restrict__ bias,
                              float* __restrict__ C) {
    const int tid = threadIdx.x;
    const int tx = tid & 15, ty = tid >> 4;
    const int brow = blockIdx.y * 64, bcol = blockIdx.x * 64;
    __shared__ float As[64][17];
    __shared__ float Ws[64][17];
    float acc[4][4] = {};
    for (int k0 = 0; k0 < K; k0 += 16) {
        __syncthreads();
        for (int i = tid; i < 64 * 16; i += 256) {
            int r = i >> 4, c = i & 15;
            As[r][c] = x[(size_t)(brow + r) * K + k0 + c];
            float wv = w[(size_t)(bcol + r) * K + k0 + c];
            Ws[r][c] = mask[(size_t)(bcol + r) * K + k0 + c] ? wv : 0.0f;
        }
        __syncthreads();
        for (int kk = 0; kk < 16; ++kk) {
            float a[4], b[4];
#pragma unroll
            for (int i = 0; i < 4; ++i) a[i] = As[ty * 4 + i][kk];
#pragma unroll
            for (int i = 0; i < 4; ++i) b[i] = Ws[tx * 4 + i][kk];
#pragma unroll
            for (int i = 0; i < 4; ++i)
#pragma unroll
                for (int j = 0; j < 4; ++j) acc[i][j] += a[i] * b[j];
        }
    }
    for (int i = 0; i < 4; ++i)
        for (int j = 0; j < 4; ++j) {
            int row = brow + ty * 4 + i, col = bcol + tx * 4 + j;
            C[(size_t)row * N + col] = acc[i][j] + bias[col];
        }
}

extern "C" void kernel_launch(void* const* d_in, const int* in_sizes, int n_in,
                              void* d_out, int out_size, void* d_ws, size_t ws_size,
                              hipStream_t stream) {
    const float* x    = (const float*)d_in[0];
    const float* w    = (const float*)d_in[1];
    const float* bias = (const float*)d_in[2];
    const int*   mask = (const int*)d_in[3];
    float* out = (float*)d_out;

    const size_t need = ((size_t)M * K + (size_t)N * K) * sizeof(unsigned short);
    if (ws_size >= need) {
        unsigned short* xb = (unsigned short*)d_ws;           // [M][K] bf16
        unsigned short* wb = xb + (size_t)M * K;              // [N][K] bf16
        (void)hipFuncSetAttribute((const void*)gemm8_bf16,
                                  hipFuncAttributeMaxDynamicSharedMemorySize,
                                  131072);
        cvt_x_kernel<<<(M * K / 4) / 256, 256, 0, stream>>>(x, xb);
        cvt_wm_kernel<<<(N * K / 4) / 256, 256, 0, stream>>>(w, mask, wb);
        gemm8_bf16<<<(M / BM) * (N / BN), 512, 131072, stream>>>(xb, wb, bias, out);
    } else {
        dim3 g(N / 64, M / 64);
        fallback_gemm<<<g, 256, 0, stream>>>(x, w, mask, bias, out);
    }
}

// Round 8
// 297.887 us; speedup vs baseline: 1.1021x; 1.1021x over previous
//
#include <hip/hip_runtime.h>
#include <hip/hip_bf16.h>
#include <stdint.h>

// ExpanderLinear: y[t,o] = sum_i x[t,i] * (w[o,i]*mask[o,i]) + bias[o]
// M=8192, K=4096, N=4096. f32 in/out, bf16 MFMA compute.
// GEMM: 256x256 tile, 8 waves, ring-4 half-K LDS units, 4 phases/K-tile.
// R8 change: register double-buffered fragment pipeline -- phase p issues
// ds_reads for phase p+1, MFMA cluster p runs on last phase's operands, so
// the LDS pipe services reads DURING the MFMA cluster (max instead of sum).
// MM before the phase barrier (read-completion sequenced pre-barrier ->
// stage-writes formally safe). Stages deepened: u1(t+1) at P1/P2,
// u0(t+2) at P3/P4; waits vmcnt(2)@P1, vmcnt(4)@P3 retire loads aged >=2
// phases only. T1 XCD swizzle + T2 LDS swizzle + T5 setprio kept.

typedef __attribute__((ext_vector_type(4))) float          f32x4;
typedef __attribute__((ext_vector_type(4))) int            i32x4;
typedef __attribute__((ext_vector_type(4))) unsigned short u16x4;
typedef __attribute__((ext_vector_type(8))) __bf16         bf16x8;

static constexpr int M = 8192;
static constexpr int N = 4096;
static constexpr int K = 4096;

#define BM 256
#define BN 256
#define NT (K / 64)

#define GLOBAL_AS(p) ((const __attribute__((address_space(1))) void*)(p))
#define LDS_AS(p)    ((__attribute__((address_space(3))) void*)(p))

__device__ __forceinline__ unsigned short f2bf(float f) {
    unsigned int u = __float_as_uint(f);
    u = (u + 0x7fffu + ((u >> 16) & 1u)) >> 16;
    return (unsigned short)u;
}

// ---- prep 1: x f32 -> bf16 ----
__global__ void cvt_x_kernel(const float* __restrict__ x,
                             unsigned short* __restrict__ out) {
    int i = blockIdx.x * blockDim.x + threadIdx.x;
    f32x4 v = ((const f32x4*)x)[i];
    u16x4 r;
    r.x = f2bf(v.x); r.y = f2bf(v.y); r.z = f2bf(v.z); r.w = f2bf(v.w);
    ((u16x4*)out)[i] = r;
}

// ---- prep 2: (w * mask) f32 -> bf16, fused ----
__global__ void cvt_wm_kernel(const float* __restrict__ w,
                              const int* __restrict__ mask,
                              unsigned short* __restrict__ out) {
    int i = blockIdx.x * blockDim.x + threadIdx.x;
    f32x4 v = ((const f32x4*)w)[i];
    i32x4 m = ((const i32x4*)mask)[i];
    u16x4 r;
    r.x = m.x ? f2bf(v.x) : (unsigned short)0;
    r.y = m.y ? f2bf(v.y) : (unsigned short)0;
    r.z = m.z ? f2bf(v.z) : (unsigned short)0;
    r.w = m.w ? f2bf(v.w) : (unsigned short)0;
    ((u16x4*)out)[i] = r;
}

// ---- main GEMM ----
// LDS: A-ring = 4 units of [256 rows][32 bf16] (16KB each), B-ring same.
// Unit for (tile t, k-half h) lives in slot (2t+h)&3.
// Swizzle (within 128B row-pair): phys3 = (((row&1)<<2)|fq) ^ ((row>>1)&7).
// LDS writes stay linear (global_load_lds); global SOURCE pre-swizzled.
__global__ void __launch_bounds__(512, 2)
gemm8_bf16(const unsigned short* __restrict__ A,   // [M][K] bf16 bits
           const unsigned short* __restrict__ B,   // [N][K] bf16 bits
           const float* __restrict__ bias,         // [N]
           float* __restrict__ C) {                // [M][N] f32
    extern __shared__ unsigned short lds[];
    unsigned short* __restrict__ Au = lds;            // 4 * 8192 elems
    unsigned short* __restrict__ Bu = lds + 32768;    // 4 * 8192 elems

    const int tid  = threadIdx.x;
    const int lane = tid & 63;
    const int wave = tid >> 6;

    // T1: XCD-aware bijective swizzle (nwg = 512, % 8 == 0)
    const int bid = blockIdx.x;
    const int swz = (bid & 7) * 64 + (bid >> 3);
    const int brow = (swz >> 4) * BM;          // ntn = 16
    const int bcol = (swz & 15) * BN;

    const int wrow = (wave >> 2) * 128;        // wave output rows
    const int wcol = (wave & 3) * 64;          // wave output cols
    const int fr = lane & 15;                  // fragment row/col
    const int fq = lane >> 4;                  // k-subgroup

    // read-side swizzle bases (byte offsets within a unit)
    const int s3r   = (((fr & 1) << 2) | fq) ^ (fr >> 1);
    const int abase = wrow * 64 + (fr >> 1) * 128 + s3r * 16;   // + m*1024
    const int bbase = wcol * 64 + (fr >> 1) * 128 + s3r * 16;   // + n*1024

    // write-side: lane's linear LDS slot -> logical (row, col) in global
    const int l8 = lane & 7, lh = lane >> 3;
    const int s3w    = l8 ^ lh;
    const int wrow_l = 2 * lh + (s3w >> 2);    // row within 16-row call block
    const int wcol_l = (s3w & 3) * 8;          // bf16 col within 32-col unit

    const unsigned short* __restrict__ Ag = A + (size_t)brow * K;
    const unsigned short* __restrict__ Bg = B + (size_t)bcol * K;

    f32x4 acc[8][4];
#pragma unroll
    for (int m = 0; m < 8; ++m)
#pragma unroll
        for (int n = 0; n < 4; ++n) acc[m][n] = (f32x4)(0.0f);

    // double-buffered fragment registers (static names, rule #20)
    bf16x8 afA[4], afB[4], bvA[4], bvB[4];

#define STG1(dst, src) __builtin_amdgcn_global_load_lds(GLOBAL_AS(src), LDS_AS(dst), 16, 0, 0)
#define STGA(slot, kcol) do {                                                   \
    STG1(Au + (slot) * 8192 + wave * 512,                                       \
         Ag + (size_t)(wave * 16 + wrow_l) * K + (kcol) + wcol_l);              \
    STG1(Au + (slot) * 8192 + (wave + 8) * 512,                                 \
         Ag + (size_t)((wave + 8) * 16 + wrow_l) * K + (kcol) + wcol_l);        \
  } while (0)
#define STGB(slot, kcol) do {                                                   \
    STG1(Bu + (slot) * 8192 + wave * 512,                                       \
         Bg + (size_t)(wave * 16 + wrow_l) * K + (kcol) + wcol_l);              \
    STG1(Bu + (slot) * 8192 + (wave + 8) * 512,                                 \
         Bg + (size_t)((wave + 8) * 16 + wrow_l) * K + (kcol) + wcol_l);        \
  } while (0)
#define LDA4(buf, unit, m0) do {                                               \
    const char* ub_ = (const char*)(Au + (unit) * 8192);                        \
    _Pragma("unroll")                                                           \
    for (int i = 0; i < 4; ++i)                                                 \
        buf[i] = *(const bf16x8*)(ub_ + abase + ((m0) + i) * 1024);             \
  } while (0)
#define LDB4(buf, unit) do {                                                    \
    const char* vb_ = (const char*)(Bu + (unit) * 8192);                        \
    _Pragma("unroll")                                                           \
    for (int n = 0; n < 4; ++n)                                                 \
        buf[n] = *(const bf16x8*)(vb_ + bbase + n * 1024);                      \
  } while (0)
#define MM4(a, b, r0) do {                                                      \
    __builtin_amdgcn_s_setprio(1);                                              \
    _Pragma("unroll")                                                           \
    for (int i = 0; i < 4; ++i)                                                 \
      _Pragma("unroll")                                                         \
      for (int n = 0; n < 4; ++n)                                               \
        acc[(r0) + i][n] = __builtin_amdgcn_mfma_f32_16x16x32_bf16(             \
            a[i], b[n], acc[(r0) + i][n], 0, 0, 0);                             \
    __builtin_amdgcn_s_setprio(0);                                              \
  } while (0)
#define BAR    __builtin_amdgcn_s_barrier()
#define FENCE  asm volatile("" ::: "memory")
#define SCHED0 __builtin_amdgcn_sched_barrier(0)
#define WVM2   asm volatile("s_waitcnt vmcnt(2)" ::: "memory")
#define WVM4   asm volatile("s_waitcnt vmcnt(4)" ::: "memory")
#define WVM8   asm volatile("s_waitcnt vmcnt(8)" ::: "memory")
#define WVM0   asm volatile("s_waitcnt vmcnt(0)" ::: "memory")

    // prologue: stage slot0 (u0(0)), slot1 (u1(0)), slot2 (u0(1));
    // drain slot0 (12 -> 8 outstanding), then preload C1's fragments.
    STGA(0, 0);  STGB(0, 0);
    STGA(1, 32); STGB(1, 32);
    STGA(2, 64); STGB(2, 64);
    WVM8;
    BAR; FENCE;
    LDA4(afA, 0, 0); LDB4(bvA, 0);

    for (int t = 0; t < NT - 1; ++t) {
        const int u0 = (2 * t) & 3;
        const int u1 = (2 * t + 1) & 3;
        const int sY = (2 * t + 3) & 3;            // u1(t+1), staged P1/P2
        const int sX = (2 * t + 4) & 3;            // u0(t+2), staged P3/P4
        const int sN = (2 * t + 2) & 3;            // u0(t+1), read at P4
        const int kY = (t + 1) * 64 + 32;
        const int kX = ((t + 2) * 64) & (K - 1);   // wrap at t=NT-2: benign
        // P1: retire {Y(t-1) both, X'(t-1) A} -- aged 4/3/2 phases, no stall
        WVM2;
        STGA(sY, kY);
        LDA4(afB, u0, 4);                          // for C2
        SCHED0;
        MM4(afA, bvA, 0);                          // C1 (read last phase)
        BAR; FENCE;
        // P2
        STGB(sY, kY);
        LDA4(afA, u1, 0); LDB4(bvB, u1);           // for C3
        SCHED0;
        MM4(afB, bvA, 4);                          // C2
        BAR; FENCE;
        // P3: retire X'(t-1) B batch (aged 3 phases) -> u0(t+1) resident
        WVM4;
        STGA(sX, kX);
        LDA4(afB, u1, 4);                          // for C4
        SCHED0;
        MM4(afA, bvB, 0);                          // C3
        BAR; FENCE;
        // P4
        STGB(sX, kX);
        LDA4(afA, sN, 0); LDB4(bvA, sN);           // for next tile's C1
        SCHED0;
        MM4(afB, bvB, 4);                          // C4
        BAR; FENCE;
    }
    {   // last tile t = NT-1: u0 = slot2, u1 = slot3; no staging
        const int u0 = (2 * (NT - 1)) & 3;
        const int u1 = (2 * (NT - 1) + 1) & 3;
        WVM0;                                      // drain tail stage batches
        BAR; FENCE;
        LDA4(afB, u0, 4);
        SCHED0;
        MM4(afA, bvA, 0);
        BAR; FENCE;
        LDA4(afA, u1, 0); LDB4(bvB, u1);
        SCHED0;
        MM4(afB, bvA, 4);
        LDA4(afB, u1, 4);
        SCHED0;
        MM4(afA, bvB, 0);
        MM4(afB, bvB, 4);
    }

    // epilogue: C/D layout col=lane&15, row=(lane>>4)*4+reg [m89/m91]
    float bv[4];
#pragma unroll
    for (int n = 0; n < 4; ++n) bv[n] = bias[bcol + wcol + n * 16 + fr];
#pragma unroll
    for (int m = 0; m < 8; ++m) {
#pragma unroll
        for (int j = 0; j < 4; ++j) {
            const int row = brow + wrow + m * 16 + fq * 4 + j;
            float* crow = C + (size_t)row * N + bcol + wcol + fr;
#pragma unroll
            for (int n = 0; n < 4; ++n) crow[n * 16] = acc[m][n][j] + bv[n];
        }
    }
#undef STG1
#undef STGA
#undef STGB
#undef LDA4
#undef LDB4
#undef MM4
#undef BAR
#undef FENCE
#undef SCHED0
#undef WVM2
#undef WVM4
#undef WVM8
#undef WVM0
}

// ---- fallback (only if ws too small): f32 vector GEMM ----
__global__ void fallback_gemm(const float* __restrict__ x,
                              const float* __restrict__ w,
                              const int* __restrict__ mask,
                              const float* __restrict__ bias,
                              float* __restrict__ C) {
    const int tid = threadIdx.x;
    const int tx = tid & 15, ty = tid >> 4;
    const int brow = blockIdx.y * 64, bcol = blockIdx.x * 64;
    __shared__ float As[64][17];
    __shared__ float Ws[64][17];
    float acc[4][4] = {};
    for (int k0 = 0; k0 < K; k0 += 16) {
        __syncthreads();
        for (int i = tid; i < 64 * 16; i += 256) {
            int r = i >> 4, c = i & 15;
            As[r][c] = x[(size_t)(brow + r) * K + k0 + c];
            float wv = w[(size_t)(bcol + r) * K + k0 + c];
            Ws[r][c] = mask[(size_t)(bcol + r) * K + k0 + c] ? wv : 0.0f;
        }
        __syncthreads();
        for (int kk = 0; kk < 16; ++kk) {
            float a[4], b[4];
#pragma unroll
            for (int i = 0; i < 4; ++i) a[i] = As[ty * 4 + i][kk];
#pragma unroll
            for (int i = 0; i < 4; ++i) b[i] = Ws[tx * 4 + i][kk];
#pragma unroll
            for (int i = 0; i < 4; ++i)
#pragma unroll
                for (int j = 0; j < 4; ++j) acc[i][j] += a[i] * b[j];
        }
    }
    for (int i = 0; i < 4; ++i)
        for (int j = 0; j < 4; ++j) {
            int row = brow + ty * 4 + i, col = bcol + tx * 4 + j;
            C[(size_t)row * N + col] = acc[i][j] + bias[col];
        }
}

extern "C" void kernel_launch(void* const* d_in, const int* in_sizes, int n_in,
                              void* d_out, int out_size, void* d_ws, size_t ws_size,
                              hipStream_t stream) {
    const float* x    = (const float*)d_in[0];
    const float* w    = (const float*)d_in[1];
    const float* bias = (const float*)d_in[2];
    const int*   mask = (const int*)d_in[3];
    float* out = (float*)d_out;

    const size_t need = ((size_t)M * K + (size_t)N * K) * sizeof(unsigned short);
    if (ws_size >= need) {
        unsigned short* xb = (unsigned short*)d_ws;           // [M][K] bf16
        unsigned short* wb = xb + (size_t)M * K;              // [N][K] bf16
        (void)hipFuncSetAttribute((const void*)gemm8_bf16,
                                  hipFuncAttributeMaxDynamicSharedMemorySize,
                                  131072);
        cvt_x_kernel<<<(M * K / 4) / 256, 256, 0, stream>>>(x, xb);
        cvt_wm_kernel<<<(N * K / 4) / 256, 256, 0, stream>>>(w, mask, wb);
        gemm8_bf16<<<(M / BM) * (N / BN), 512, 131072, stream>>>(xb, wb, bias, out);
    } else {
        dim3 g(N / 64, M / 64);
        fallback_gemm<<<g, 256, 0, stream>>>(x, w, mask, bias, out);
    }
}